// Round 6
// baseline (134.541 us; speedup 1.0000x reference)
//
#include <hip/hip_runtime.h>

// spec (32, 4000, 161, 2) f32.
//   pow[b,t,k]  = re^2 + im^2
//   g0[b,t]     = sqrt((2*sum(pow) - pow[0] - pow[160]) / 320)
//   gain[b,t]   = EMA over t: c = 0.9c + 0.1*g0  (gain[b,0]=g0[b,0])
//   new_spec    = spec / (gain + 0.001)
// Outputs flat-concat: new_spec (41,216,000 f32) then gain (128,000 f32).
//
// Single-kernel design: each block owns (batch b, 500-frame chunk c) and
// recomputes the 383-frame g0 halo itself (truncated EMA window, exact to
// ~1e-17), so no inter-kernel dependency / grid sync is needed.

typedef float f32x4 __attribute__((ext_vector_type(4)));
typedef float f32x2 __attribute__((ext_vector_type(2)));

#define B_SZ 32
#define T_SZ 4000
#define FRAME_F 322              // floats per frame (161 bins * 2)
#define FRAMES (B_SZ * T_SZ)
#define N_SPEC ((size_t)FRAMES * FRAME_F)  // 41,216,000
#define EMA_W 384                // 0.9^384 ~ 4e-18: below f32 resolution
#define HALO (EMA_W - 1)         // 383
#define BLOCK 1024               // 16 waves
#define CHUNK 500                // frames per block; 4000/500 = 8 chunks
#define NCHUNK (T_SZ / CHUNK)    // 8  -> grid 8*32 = 256 = 1 block/CU
#define C4 (CHUNK * FRAME_F / 4) // 40250 f32x4 per chunk (exact)
#define XS_MAX (CHUNK + HALO)    // 883

__global__ __launch_bounds__(BLOCK) void k_fused_all(
    const float* __restrict__ spec, float* __restrict__ out,
    float* __restrict__ gain_out) {
  __shared__ float xs[XS_MAX];     // g0 window
  __shared__ float inv_s[CHUNK];   // 1/(gain+1e-3) for owned frames

  int c  = blockIdx.x;
  int b  = blockIdx.y;
  int t0 = c * CHUNK;
  int lo = t0 - HALO; if (lo < 0) lo = 0;
  int hiF  = t0 + CHUNK;
  int lane = threadIdx.x & 63;
  int wv   = threadIdx.x >> 6;     // wave id 0..15
  int tid  = threadIdx.x;

  const float* srow = spec + (size_t)b * T_SZ * FRAME_F;

  // ---- Phase A: g0 for frames [lo, hiF), one wave per frame round-robin ----
  for (int f = lo + wv; f < hiF; f += 16) {
    const float* fp = srow + (size_t)f * FRAME_F;
    f32x4 v0 = *(const f32x4*)(fp + lane * 4);       // pairs 0..127
    float s0 = v0.x * v0.x + v0.y * v0.y;
    float s1 = v0.z * v0.z + v0.w * v0.w;
    float acc = 2.0f * (s0 + s1);
    if (lane == 0) acc -= s0;                        // pow[0] weight 1
    if (lane < 16) {                                 // pairs 128..159
      f32x4 v1 = *(const f32x4*)(fp + (64 + lane) * 4);
      acc += 2.0f * (v1.x * v1.x + v1.y * v1.y + v1.z * v1.z + v1.w * v1.w);
    } else if (lane == 16) {                         // pair 160, weight 1
      f32x2 v2 = *(const f32x2*)(fp + 320);
      acc += v2.x * v2.x + v2.y * v2.y;
    }
#pragma unroll
    for (int off = 32; off > 0; off >>= 1) acc += __shfl_xor(acc, off, 64);
    if (lane == 0) xs[f - lo] = sqrtf(acc * (1.0f / 320.0f));
  }
  __syncthreads();

  // ---- Phase B: truncated-window EMA for the 500 owned frames ----
  if (tid < CHUNK) {
    int t = t0 + tid;
    int s = t - HALO; if (s < 1) s = 1;
    float cc = (s == 1) ? xs[0] : 0.f;               // lo==0 whenever s==1
    for (int k = s; k <= t; ++k) cc = cc * 0.9f + xs[k - lo] * 0.1f;
    gain_out[b * T_SZ + t] = cc;
    inv_s[tid] = 1.0f / (cc + 0.001f);
  }
  __syncthreads();

  // ---- Phase C: stream out = spec * inv, 40250 f32x4 (chunk-aligned) ----
  size_t base4 = ((size_t)b * T_SZ + t0) * FRAME_F / 4;
  const f32x4* sp = (const f32x4*)spec + base4;
  f32x4*       op = (f32x4*)out  + base4;
#pragma unroll 4
  for (int i = tid; i < C4; i += BLOCK) {
    f32x4 v = sp[i];
    unsigned p0 = (unsigned)(2 * i);                 // local pair idx of (v.x,v.y)
    unsigned lf = p0 / 161u;                         // local frame 0..499 (magic mul)
    unsigned r  = p0 - lf * 161u;
    unsigned lf1 = lf + (r == 160u);                 // frame of second pair
    float i0 = inv_s[lf];
    float i1 = inv_s[lf1];
    f32x4 rr;
    rr.x = v.x * i0; rr.y = v.y * i0;
    rr.z = v.z * i1; rr.w = v.w * i1;
    // nt store: don't let the write stream evict spec from L3
    __builtin_nontemporal_store(rr, op + i);
  }
}

extern "C" void kernel_launch(void* const* d_in, const int* in_sizes, int n_in,
                              void* d_out, int out_size, void* d_ws, size_t ws_size,
                              hipStream_t stream) {
  const float* spec = (const float*)d_in[0];
  float* out  = (float*)d_out;
  float* gain = out + N_SPEC;        // gain output lives in the d_out tail

  dim3 grid(NCHUNK, B_SZ);           // (8, 32) = 256 blocks = 1 per CU
  k_fused_all<<<grid, BLOCK, 0, stream>>>(spec, out, gain);
}

// Round 7
// 133.710 us; speedup vs baseline: 1.0062x; 1.0062x over previous
//
#include <hip/hip_runtime.h>

// spec (32, 4000, 161, 2) f32.
//   pow[b,t,k]  = re^2 + im^2
//   g0[b,t]     = sqrt((2*sum(pow[1..159]) + pow[0] + pow[160]) / 320)
//   gain[b,t]   = EMA over t: c = 0.9c + 0.1*g0  (gain[b,0]=g0[b,0])
//   new_spec    = spec / (gain + 0.001)
// Outputs flat-concat: new_spec (41,216,000 f32) then gain (128,000 f32).
//
// Single-pass: block = (batch b, 250-frame chunk). Recomputes the 383-frame
// g0 halo itself (truncated EMA window, error ~1e-17) -> no inter-kernel dep.
// Phase A is thread-per-frame (no cross-lane ops, 80 independent loads/thread).

typedef float f32x4 __attribute__((ext_vector_type(4)));
typedef float f32x2 __attribute__((ext_vector_type(2)));

#define B_SZ 32
#define T_SZ 4000
#define FRAME_F 322              // floats per frame (161 bins * 2)
#define N_SPEC ((size_t)B_SZ * T_SZ * FRAME_F)  // 41,216,000
#define EMA_W 384                // 0.9^384 ~ 4e-18: below f32 resolution
#define HALO (EMA_W - 1)         // 383
#define BLOCK 512                // 8 waves
#define CHUNK 250                // frames per block; 16 chunks/row
#define NCHUNK (T_SZ / CHUNK)    // 16 -> grid 16*32 = 512 = 2 blocks/CU
#define C4 (CHUNK * FRAME_F / 4) // 20125 f32x4 per chunk (exact)
#define XS_MAX (CHUNK + HALO)    // 633

__global__ __launch_bounds__(BLOCK) void k_fused_all(
    const float* __restrict__ spec, float* __restrict__ out,
    float* __restrict__ gain_out) {
  __shared__ float xs[XS_MAX];     // g0 window
  __shared__ float inv_s[CHUNK];   // 1/(gain+1e-3) for owned frames

  int c  = blockIdx.x;
  int b  = blockIdx.y;
  int t0 = c * CHUNK;
  int lo = t0 - HALO; if (lo < 0) lo = 0;
  int hiF = t0 + CHUNK;
  int tid = threadIdx.x;

  const float* srow = spec + (size_t)b * T_SZ * FRAME_F;

  // ---- Phase A: g0 for frames [lo, hiF), one THREAD per frame ----
  for (int f = lo + tid; f < hiF; f += BLOCK) {
    const float* fp = srow + (size_t)f * FRAME_F;
    float ax = 0.f, ay = 0.f, az = 0.f, aw = 0.f;
#pragma unroll 8
    for (int j = 0; j < 80; ++j) {           // pairs 0..159
      f32x4 v = *(const f32x4*)(fp + j * 4);
      ax += v.x * v.x; ay += v.y * v.y;
      az += v.z * v.z; aw += v.w * v.w;
    }
    f32x2 v0 = *(const f32x2*)(fp);          // pair 0 (L1 hit)
    f32x2 vL = *(const f32x2*)(fp + 320);    // pair 160
    float total = (ax + az) + (ay + aw);     // sum pow[0..159]
    float pow0  = v0.x * v0.x + v0.y * v0.y;
    float powL  = vL.x * vL.x + vL.y * vL.y;
    float wnum  = 2.f * total - pow0 + powL; // 2*sum(1..159)+pow0+pow160
    xs[f - lo] = sqrtf(wnum * (1.0f / 320.0f));
  }
  __syncthreads();

  // ---- Phase B: truncated-window EMA for the owned frames ----
  if (tid < CHUNK) {
    int t = t0 + tid;
    int s = t - HALO; if (s < 1) s = 1;
    float cc = (s == 1) ? xs[0] : 0.f;       // lo==0 whenever s==1
    for (int k = s; k <= t; ++k) cc = cc * 0.9f + xs[k - lo] * 0.1f;
    gain_out[b * T_SZ + t] = cc;
    inv_s[tid] = 1.0f / (cc + 0.001f);
  }
  __syncthreads();

  // ---- Phase C: stream out = spec * inv, 20125 f32x4 (chunk-aligned) ----
  size_t base4 = ((size_t)b * T_SZ + t0) * FRAME_F / 4;
  const f32x4* sp = (const f32x4*)spec + base4;
  f32x4*       op = (f32x4*)out  + base4;
#pragma unroll 4
  for (int i = tid; i < C4; i += BLOCK) {
    f32x4 v = sp[i];
    unsigned p0 = (unsigned)(2 * i);         // local pair idx of (v.x,v.y)
    unsigned lf = p0 / 161u;                 // local frame 0..249 (magic mul)
    unsigned r  = p0 - lf * 161u;
    unsigned lf1 = lf + (r == 160u);         // frame of second pair
    float i0 = inv_s[lf];
    float i1 = inv_s[lf1];
    f32x4 rr;
    rr.x = v.x * i0; rr.y = v.y * i0;
    rr.z = v.z * i1; rr.w = v.w * i1;
    // nt store: keep the write stream from evicting spec
    __builtin_nontemporal_store(rr, op + i);
  }
}

extern "C" void kernel_launch(void* const* d_in, const int* in_sizes, int n_in,
                              void* d_out, int out_size, void* d_ws, size_t ws_size,
                              hipStream_t stream) {
  const float* spec = (const float*)d_in[0];
  float* out  = (float*)d_out;
  float* gain = out + N_SPEC;        // gain output lives in the d_out tail

  dim3 grid(NCHUNK, B_SZ);           // (16, 32) = 512 blocks = 2 per CU
  k_fused_all<<<grid, BLOCK, 0, stream>>>(spec, out, gain);
}

// Round 8
// 119.974 us; speedup vs baseline: 1.1214x; 1.1145x over previous
//
#include <hip/hip_runtime.h>

// spec (32, 4000, 161, 2) f32.
//   pow[b,t,k]  = re^2 + im^2
//   g0[b,t]     = sqrt((2*sum(pow[1..159]) + pow[0] + pow[160]) / 320)
//   gain[b,t]   = EMA over t: c = 0.9c + 0.1*g0  (gain[b,0]=g0[b,0])
//   new_spec    = spec / (gain + 0.001)
// Outputs flat-concat: new_spec (41,216,000 f32) then gain (128,000 f32).
//
// One dispatch. Block (b,c) owns 200 frames: computes their g0 (single spec
// read, no halo amplification), publishes g0 via threadfence+flag, spin-waits
// its 2 predecessor chunks (g0 halo is 383 FLOATS, trivial), runs the
// truncated-window EMA (0.9^384 < f32 eps -> exact), then applies the gain
// streaming its own chunk while it is still L3-hot from phase A.
// Grid 640 blocks @ 512 thr (<=3 blocks/CU, capacity 4) -> all co-resident,
// so the spin cannot deadlock. Flags zeroed per launch via hipMemsetAsync.

typedef float f32x4 __attribute__((ext_vector_type(4)));
typedef float f32x2 __attribute__((ext_vector_type(2)));

#define B_SZ 32
#define T_SZ 4000
#define FRAME_F 322              // floats per frame (161 bins * 2)
#define N_SPEC ((size_t)B_SZ * T_SZ * FRAME_F)  // 41,216,000
#define HALO 383                 // EMA window-1; 0.9^384 ~ 4e-18
#define BLOCK 512                // 8 waves
#define CHUNK 200                // frames per block; 200*322/4 = 16100 exact
#define NCHUNK (T_SZ / CHUNK)    // 20 -> grid 20*32 = 640 blocks
#define C4 (CHUNK * FRAME_F / 4) // 16100 f32x4 per chunk
#define XS_N (HALO + CHUNK)      // 583

__global__ __launch_bounds__(BLOCK) void k_flow(
    const float* __restrict__ spec, float* __restrict__ out,
    float* __restrict__ gain_out, float* __restrict__ g0,
    int* __restrict__ flags) {
  __shared__ float xs[XS_N];       // g0 window [lo, t0+CHUNK)
  __shared__ float inv_s[CHUNK];   // 1/(gain+1e-3) for owned frames

  int c  = blockIdx.x;
  int b  = blockIdx.y;
  int t0 = c * CHUNK;
  int lo = t0 - HALO; if (lo < 0) lo = 0;
  int hn = t0 - lo;                // halo count: 0 / 200 / 383
  int tid  = threadIdx.x;
  int lane = tid & 63;
  int wv   = tid >> 6;             // wave 0..7

  const float* srow = spec + (size_t)b * T_SZ * FRAME_F;
  float* grow = g0 + b * T_SZ;

  // ---- Phase A: g0 for OWN frames, one wave per frame (coalesced) ----
  for (int lf = wv; lf < CHUNK; lf += 8) {
    const float* fp = srow + (size_t)(t0 + lf) * FRAME_F;
    f32x4 v0 = *(const f32x4*)(fp + lane * 4);       // pairs 0..127
    float s0 = v0.x * v0.x + v0.y * v0.y;
    float s1 = v0.z * v0.z + v0.w * v0.w;
    float acc = 2.0f * (s0 + s1);
    if (lane == 0) acc -= s0;                        // pow[0] weight 1
    if (lane < 16) {                                 // pairs 128..159
      f32x4 v1 = *(const f32x4*)(fp + (64 + lane) * 4);
      acc += 2.0f * (v1.x * v1.x + v1.y * v1.y + v1.z * v1.z + v1.w * v1.w);
    } else if (lane == 16) {                         // pair 160, weight 1
      f32x2 v2 = *(const f32x2*)(fp + 320);
      acc += v2.x * v2.x + v2.y * v2.y;
    }
#pragma unroll
    for (int off = 32; off > 0; off >>= 1) acc += __shfl_xor(acc, off, 64);
    if (lane == 0) {
      float g = sqrtf(acc * (1.0f / 320.0f));
      xs[hn + lf] = g;                               // own slot in window
      grow[t0 + lf] = g;                             // publish for successors
    }
  }
  __syncthreads();                 // all own g0 stores issued & drained

  // ---- Publish flag, then wait on the 2 predecessor chunks ----
  if (tid == 0) {
    __threadfence();                                 // release own g0
    atomicExch(&flags[b * NCHUNK + c], 1);
    for (int p = c - 1; p >= 0 && p >= c - 2; --p)
      while (atomicAdd(&flags[b * NCHUNK + p], 0) == 0) {}
    __threadfence();                                 // acquire their g0
  }
  __syncthreads();

  // ---- Load halo g0 [lo, t0) ----
  for (int i = tid; i < hn; i += BLOCK) xs[i] = grow[lo + i];
  __syncthreads();

  // ---- Phase B: truncated-window EMA for owned frames ----
  if (tid < CHUNK) {
    int t = t0 + tid;
    int s = t - HALO; if (s < 1) s = 1;
    float cc = (s == 1) ? xs[0] : 0.f;               // lo==0 whenever s==1
    for (int k = s; k <= t; ++k) cc = cc * 0.9f + xs[k - lo] * 0.1f;
    gain_out[b * T_SZ + t] = cc;
    inv_s[tid] = 1.0f / (cc + 0.001f);
  }
  __syncthreads();

  // ---- Phase C: stream out = spec * inv (chunk is L3-hot from phase A) ----
  size_t base4 = ((size_t)b * T_SZ + t0) * FRAME_F / 4;
  const f32x4* sp = (const f32x4*)spec + base4;
  f32x4*       op = (f32x4*)out  + base4;
#pragma unroll 4
  for (int i = tid; i < C4; i += BLOCK) {
    f32x4 v = sp[i];
    unsigned p0 = (unsigned)(2 * i);                 // local pair idx of (v.x,v.y)
    unsigned lf = p0 / 161u;                         // local frame (magic mul)
    unsigned r  = p0 - lf * 161u;
    unsigned lf1 = lf + (r == 160u);                 // frame of second pair
    float i0 = inv_s[lf];
    float i1 = inv_s[lf1];
    f32x4 rr;
    rr.x = v.x * i0; rr.y = v.y * i0;
    rr.z = v.z * i1; rr.w = v.w * i1;
    // nt store: keep the write stream from evicting spec in L3
    __builtin_nontemporal_store(rr, op + i);
  }
}

extern "C" void kernel_launch(void* const* d_in, const int* in_sizes, int n_in,
                              void* d_out, int out_size, void* d_ws, size_t ws_size,
                              hipStream_t stream) {
  const float* spec = (const float*)d_in[0];
  float* out  = (float*)d_out;
  float* gain = out + N_SPEC;          // gain output lives in the d_out tail
  float* g0   = (float*)d_ws;          // 128000 f32
  int*   flags = (int*)(g0 + B_SZ * T_SZ);  // 640 ints

  hipMemsetAsync(flags, 0, B_SZ * NCHUNK * sizeof(int), stream);

  dim3 grid(NCHUNK, B_SZ);             // (20, 32) = 640 blocks
  k_flow<<<grid, BLOCK, 0, stream>>>(spec, out, gain, g0, flags);
}

// Round 9
// 109.378 us; speedup vs baseline: 1.2301x; 1.0969x over previous
//
#include <hip/hip_runtime.h>

// spec (32, 4000, 161, 2) f32.
//   pow[b,t,k]  = re^2 + im^2
//   g0[b,t]     = sqrt((2*sum(pow[1..159]) + pow[0] + pow[160]) / 320)
//   gain[b,t]   = EMA over t: c = 0.9c + 0.1*g0  (gain[b,0]=g0[b,0])
//   new_spec    = spec / (gain + 0.001)
// Outputs flat-concat: new_spec (41,216,000 f32) then gain (128,000 f32).
//
// 3-kernel split. Infinity Cache is memory-side (not flushed across
// dispatches), so K3's spec re-read is L3-hit after K1's full read.
// K3 uses PLAIN stores (nt-store suspect removed) + LDS inv panel.

typedef float f32x4 __attribute__((ext_vector_type(4)));
typedef float f32x2 __attribute__((ext_vector_type(2)));

#define B_SZ 32
#define T_SZ 4000
#define FRAME_F 322              // floats per frame (161 bins * 2)
#define FRAMES (B_SZ * T_SZ)     // 128000
#define N_SPEC ((size_t)FRAMES * FRAME_F)  // 41,216,000
#define N4 (N_SPEC / 4)          // 10,304,000 f32x4 (exact)
#define EMA_W 384                // 0.9^384 ~ 4e-18: below f32 resolution
#define HALO (EMA_W - 1)         // 383
#define BLOCK 256
#define U 16                     // f32x4 per thread in k_apply
#define APB (BLOCK * U)          // 4096 f32x4 per apply block

// ---- K1: per-frame gain g0. One 64-lane wave per frame, one-shot. ----
__global__ __launch_bounds__(BLOCK) void k_frame_gain(
    const float* __restrict__ spec, float* __restrict__ g0) {
  int gtid = blockIdx.x * BLOCK + threadIdx.x;
  int wid  = gtid >> 6;          // frame id
  int lane = threadIdx.x & 63;
  if (wid >= FRAMES) return;

  const float* fp = spec + (size_t)wid * FRAME_F;
  f32x4 v0 = *(const f32x4*)(fp + lane * 4);       // pairs 0..127
  float s0 = v0.x * v0.x + v0.y * v0.y;
  float s1 = v0.z * v0.z + v0.w * v0.w;
  float acc = 2.0f * (s0 + s1);
  if (lane == 0) acc -= s0;                        // pow[0] weight 1
  if (lane < 16) {                                 // pairs 128..159
    f32x4 v1 = *(const f32x4*)(fp + (64 + lane) * 4);
    acc += 2.0f * (v1.x * v1.x + v1.y * v1.y + v1.z * v1.z + v1.w * v1.w);
  } else if (lane == 16) {                         // pair 160, weight 1
    f32x2 v2 = *(const f32x2*)(fp + 320);
    acc += v2.x * v2.x + v2.y * v2.y;
  }
#pragma unroll
  for (int off = 32; off > 0; off >>= 1) acc += __shfl_xor(acc, off, 64);
  if (lane == 0) g0[wid] = sqrtf(acc * (1.0f / 320.0f));
}

// ---- K2: EMA via truncated window (exact for t < EMA_W); emits gain+inv ----
__global__ __launch_bounds__(BLOCK) void k_ema(
    const float* __restrict__ g0, float* __restrict__ gain_out,
    float* __restrict__ inv_out) {
  __shared__ float xs[HALO + 1 + 256];
  int b  = blockIdx.y;
  int t0 = blockIdx.x * 256;
  int lo = t0 - HALO; if (lo < 0) lo = 0;
  int hi = t0 + 256; if (hi > T_SZ) hi = T_SZ;     // exclusive
  int n  = hi - lo;
  const float* gb = g0 + b * T_SZ;

  for (int i = threadIdx.x; i < n; i += BLOCK) xs[i] = gb[lo + i];
  __syncthreads();

  int t = t0 + (int)threadIdx.x;
  if (t >= T_SZ) return;
  int s = t - HALO; if (s < 1) s = 1;
  float c = (s == 1) ? xs[0] : 0.f;                // lo==0 whenever s==1
  for (int k = s; k <= t; ++k) c = c * 0.9f + xs[k - lo] * 0.1f;
  gain_out[b * T_SZ + t] = c;
  inv_out[b * T_SZ + t]  = 1.0f / (c + 0.001f);
}

// ---- K3: out = spec * inv[frame]; one-shot, 16 f32x4/thread, PLAIN stores ----
__global__ __launch_bounds__(BLOCK) void k_apply(
    const float* __restrict__ spec, const float* __restrict__ inv_g,
    float* __restrict__ out) {
  __shared__ float linv[56];                       // block spans <= 52 frames
  size_t b0 = (size_t)blockIdx.x * APB;
  unsigned fA = (unsigned)(2 * b0) / 161u;
  size_t lastI = b0 + APB - 1; if (lastI > N4 - 1) lastI = N4 - 1;
  unsigned fB = (unsigned)(2 * lastI + 1) / 161u;
  if (threadIdx.x < fB - fA + 1) linv[threadIdx.x] = inv_g[fA + threadIdx.x];
  __syncthreads();

#pragma unroll
  for (int k = 0; k < U; ++k) {
    size_t i = b0 + threadIdx.x + (size_t)k * BLOCK;
    if (i < N4) {
      f32x4 v = ((const f32x4*)spec)[i];
      unsigned p = (unsigned)(2 * i);              // pair idx of (v.x,v.y)
      unsigned q = p / 161u;                       // its frame (magic mul)
      unsigned r = p - q * 161u;
      unsigned l0 = q - fA;
      unsigned l1 = l0 + (r == 160u);              // frame of second pair
      float i0 = linv[l0];
      float i1 = linv[l1];
      f32x4 rr;
      rr.x = v.x * i0; rr.y = v.y * i0;
      rr.z = v.z * i1; rr.w = v.w * i1;
      ((f32x4*)out)[i] = rr;                       // plain store
    }
  }
}

extern "C" void kernel_launch(void* const* d_in, const int* in_sizes, int n_in,
                              void* d_out, int out_size, void* d_ws, size_t ws_size,
                              hipStream_t stream) {
  const float* spec = (const float*)d_in[0];
  float* out   = (float*)d_out;
  float* gain  = out + N_SPEC;       // gain output lives in the d_out tail
  float* g0    = (float*)d_ws;       // 128000 f32
  float* inv_g = g0 + FRAMES;        // 128000 f32

  // K1: one-shot, 4 frames (waves) per block
  k_frame_gain<<<(FRAMES + 3) / 4, BLOCK, 0, stream>>>(spec, g0);

  // K2: (16, 32) grid
  dim3 g2((T_SZ + 255) / 256, B_SZ);
  k_ema<<<g2, BLOCK, 0, stream>>>(g0, gain, inv_g);

  // K3: one-shot, 4096 f32x4 per block
  int blocks3 = (int)((N4 + APB - 1) / APB);       // 2516
  k_apply<<<blocks3, BLOCK, 0, stream>>>(spec, inv_g, out);
}

// Round 10
// 97.282 us; speedup vs baseline: 1.3830x; 1.1243x over previous
//
#include <hip/hip_runtime.h>

// spec (32, 4000, 161, 2) f32.
//   pow[b,t,k]  = re^2 + im^2
//   g0[b,t]     = sqrt((2*sum(pow[1..159]) + pow[0] + pow[160]) / 320)
//   gain[b,t]   = EMA over t: c = 0.9c + 0.1*g0  (gain[b,0]=g0[b,0])
//   new_spec    = spec / (gain + 0.001)
// Outputs flat-concat: new_spec (41,216,000 f32) then gain (128,000 f32).
//
// K1 is THREAD-per-frame (80 independent f32x4 loads, unroll 10) -> MLP-rich,
// no shfl chains (R8 showed wave-per-frame phase A is latency-bound).
// K3 is the flat nt-store stream (R9 showed plain stores regress).

typedef float f32x4 __attribute__((ext_vector_type(4)));
typedef float f32x2 __attribute__((ext_vector_type(2)));

#define B_SZ 32
#define T_SZ 4000
#define FRAME_F 322              // floats per frame (161 bins * 2)
#define FRAMES (B_SZ * T_SZ)     // 128000
#define N_SPEC ((size_t)FRAMES * FRAME_F)  // 41,216,000
#define N4 (N_SPEC / 4)          // 10,304,000 f32x4 (exact)
#define EMA_W 384                // 0.9^384 ~ 4e-18: below f32 resolution
#define HALO (EMA_W - 1)         // 383
#define BLOCK 256

// ---- K1: per-frame gain g0. One THREAD per frame, 80 f32x4 streamed. ----
__global__ __launch_bounds__(BLOCK) void k_frame_gain(
    const float* __restrict__ spec, float* __restrict__ g0) {
  int wid = blockIdx.x * BLOCK + threadIdx.x;      // frame id
  if (wid >= FRAMES) return;
  const float* fp = spec + (size_t)wid * FRAME_F;

  float ax = 0.f, ay = 0.f, az = 0.f, aw = 0.f;
#pragma unroll 10
  for (int j = 0; j < 80; ++j) {                   // pairs 0..159
    f32x4 v = *(const f32x4*)(fp + j * 4);
    ax += v.x * v.x; ay += v.y * v.y;
    az += v.z * v.z; aw += v.w * v.w;
  }
  f32x2 v0 = *(const f32x2*)(fp);                  // pair 0 (L1 hit)
  f32x2 vL = *(const f32x2*)(fp + 320);            // pair 160
  float total = (ax + az) + (ay + aw);             // sum pow[0..159]
  float pow0  = v0.x * v0.x + v0.y * v0.y;
  float powL  = vL.x * vL.x + vL.y * vL.y;
  float wnum  = 2.f * total - pow0 + powL;         // 2*sum(1..159)+p0+p160
  g0[wid] = sqrtf(wnum * (1.0f / 320.0f));
}

// ---- K2: EMA via truncated window (exact for t < EMA_W); emits gain+inv ----
__global__ __launch_bounds__(BLOCK) void k_ema(
    const float* __restrict__ g0, float* __restrict__ gain_out,
    float* __restrict__ inv_out) {
  __shared__ float xs[HALO + 1 + 256];
  int b  = blockIdx.y;
  int t0 = blockIdx.x * 256;
  int lo = t0 - HALO; if (lo < 0) lo = 0;
  int hi = t0 + 256; if (hi > T_SZ) hi = T_SZ;     // exclusive
  int n  = hi - lo;
  const float* gb = g0 + b * T_SZ;

  for (int i = threadIdx.x; i < n; i += BLOCK) xs[i] = gb[lo + i];
  __syncthreads();

  int t = t0 + (int)threadIdx.x;
  if (t >= T_SZ) return;
  int s = t - HALO; if (s < 1) s = 1;
  float c = (s == 1) ? xs[0] : 0.f;                // lo==0 whenever s==1
  for (int k = s; k <= t; ++k) c = c * 0.9f + xs[k - lo] * 0.1f;
  gain_out[b * T_SZ + t] = c;
  inv_out[b * T_SZ + t]  = 1.0f / (c + 0.001f);
}

// ---- K3: out = spec * inv[frame]; flat one-shot f32x4, nt stores ----
__global__ __launch_bounds__(BLOCK) void k_apply(
    const float* __restrict__ spec, const float* __restrict__ inv_g,
    float* __restrict__ out) {
  size_t i = (size_t)blockIdx.x * BLOCK + threadIdx.x;   // f32x4 index
  if (i >= N4) return;
  f32x4 v = ((const f32x4*)spec)[i];
  unsigned p0 = (unsigned)(2 * i);                 // pair idx of (v.x,v.y)
  unsigned f0 = p0 / 161u;                         // frame (magic mul)
  unsigned r  = p0 - f0 * 161u;
  unsigned f1 = f0 + (r == 160u);                  // frame of second pair
  float i0 = inv_g[f0];
  float i1 = inv_g[f1];
  f32x4 rr;
  rr.x = v.x * i0; rr.y = v.y * i0;
  rr.z = v.z * i1; rr.w = v.w * i1;
  // nt store: don't evict spec from caches with the write stream
  __builtin_nontemporal_store(rr, (f32x4*)out + i);
}

extern "C" void kernel_launch(void* const* d_in, const int* in_sizes, int n_in,
                              void* d_out, int out_size, void* d_ws, size_t ws_size,
                              hipStream_t stream) {
  const float* spec = (const float*)d_in[0];
  float* out   = (float*)d_out;
  float* gain  = out + N_SPEC;       // gain output lives in the d_out tail
  float* g0    = (float*)d_ws;       // 128000 f32
  float* inv_g = g0 + FRAMES;        // 128000 f32

  // K1: thread-per-frame, 500 blocks
  k_frame_gain<<<(FRAMES + BLOCK - 1) / BLOCK, BLOCK, 0, stream>>>(spec, g0);

  // K2: (16, 32) grid
  dim3 g2((T_SZ + 255) / 256, B_SZ);
  k_ema<<<g2, BLOCK, 0, stream>>>(g0, gain, inv_g);

  // K3: flat one-shot, 40250 blocks
  k_apply<<<(int)((N4 + BLOCK - 1) / BLOCK), BLOCK, 0, stream>>>(spec, inv_g, out);
}

// Round 11
// 92.785 us; speedup vs baseline: 1.4500x; 1.0485x over previous
//
#include <hip/hip_runtime.h>

// spec (32, 4000, 161, 2) f32.
//   pow[b,t,k]  = re^2 + im^2
//   g0[b,t]     = sqrt((2*sum(pow[1..159]) + pow[0] + pow[160]) / 320)
//   gain[b,t]   = EMA over t: c = 0.9c + 0.1*g0  (gain[b,0]=g0[b,0])
//   new_spec    = spec / (gain + 0.001)
// Outputs flat-concat: new_spec (41,216,000 f32) then gain (128,000 f32).
//
// K1: 2 frames per 8-lane group -> every load instr consumes whole 64B lines
// exactly once (no L1-dependent line reassembly), 21 indep loads/lane.
// K2: truncated-window EMA (0.9^384 < f32 eps -> exact), also emits 1/(g+1e-3).
// K3: flat f32x4 nt-store stream (proven R2/R10).

typedef float f32x4 __attribute__((ext_vector_type(4)));
typedef float f32x2 __attribute__((ext_vector_type(2)));

#define B_SZ 32
#define T_SZ 4000
#define FRAME_F 322              // floats per frame (161 bins * 2)
#define FRAMES (B_SZ * T_SZ)     // 128000
#define N_SPEC ((size_t)FRAMES * FRAME_F)  // 41,216,000
#define N4 (N_SPEC / 4)          // 10,304,000 f32x4 (exact)
#define EMA_W 384                // 0.9^384 ~ 4e-18: below f32 resolution
#define HALO (EMA_W - 1)         // 383
#define BLOCK 256
#define NGROUPS (FRAMES / 2)     // 64000 8-lane groups (2 frames each)

// ---- K1: per-frame gain g0; 2 frames per 8-lane group, whole-line loads ----
__global__ __launch_bounds__(BLOCK) void k_frame_gain(
    const float* __restrict__ spec, float* __restrict__ g0) {
  int grp = (blockIdx.x * BLOCK + threadIdx.x) >> 3;   // group id
  int sub = threadIdx.x & 7;                           // lane in group
  if (grp >= NGROUPS) return;

  const float* base = spec + (size_t)grp * 644;        // 2 frames = 644 floats
  float accA = 0.f, accB = 0.f;                        // sums of pow over frames A,B
  float pw0A = 0.f, pw160A = 0.f, pw0B = 0.f, pw160B = 0.f;

#pragma unroll
  for (int k = 0; k < 21; ++k) {
    int idx = k * 8 + sub;                             // f32x4 idx in [0,161)
    if (idx < 161) {
      f32x4 v = *(const f32x4*)(base + idx * 4);
      float s01 = v.x * v.x + v.y * v.y;
      float s23 = v.z * v.z + v.w * v.w;
      if (idx < 80) {
        accA += s01 + s23;
        if (idx == 0) pw0A = s01;                      // floats 0,1   (sub==0)
      } else if (idx == 80) {                          // straddle (sub==0)
        accA += s01; accB += s23;
        pw160A = s01;                                  // floats 320,321
        pw0B   = s23;                                  // floats 322,323
      } else {
        accB += s01 + s23;
        if (idx == 160) pw160B = s23;                  // floats 642,643 (sub==0)
      }
    }
  }
#pragma unroll
  for (int off = 1; off < 8; off <<= 1) {
    accA += __shfl_xor(accA, off, 64);
    accB += __shfl_xor(accB, off, 64);
  }
  if (sub == 0) {                                      // endpoint pows live here
    f32x2 g;
    g.x = sqrtf((2.f * accA - pw0A - pw160A) * (1.0f / 320.0f));
    g.y = sqrtf((2.f * accB - pw0B - pw160B) * (1.0f / 320.0f));
    *(f32x2*)(g0 + 2 * grp) = g;
  }
}

// ---- K2: EMA via truncated window (exact for t < EMA_W); emits gain+inv ----
__global__ __launch_bounds__(BLOCK) void k_ema(
    const float* __restrict__ g0, float* __restrict__ gain_out,
    float* __restrict__ inv_out) {
  __shared__ float xs[HALO + 1 + 256];
  int b  = blockIdx.y;
  int t0 = blockIdx.x * 256;
  int lo = t0 - HALO; if (lo < 0) lo = 0;
  int hi = t0 + 256; if (hi > T_SZ) hi = T_SZ;     // exclusive
  int n  = hi - lo;
  const float* gb = g0 + b * T_SZ;

  for (int i = threadIdx.x; i < n; i += BLOCK) xs[i] = gb[lo + i];
  __syncthreads();

  int t = t0 + (int)threadIdx.x;
  if (t >= T_SZ) return;
  int s = t - HALO; if (s < 1) s = 1;
  float c = (s == 1) ? xs[0] : 0.f;                // lo==0 whenever s==1
  for (int k = s; k <= t; ++k) c = c * 0.9f + xs[k - lo] * 0.1f;
  gain_out[b * T_SZ + t] = c;
  inv_out[b * T_SZ + t]  = 1.0f / (c + 0.001f);
}

// ---- K3: out = spec * inv[frame]; flat one-shot f32x4, nt stores ----
__global__ __launch_bounds__(BLOCK) void k_apply(
    const float* __restrict__ spec, const float* __restrict__ inv_g,
    float* __restrict__ out) {
  size_t i = (size_t)blockIdx.x * BLOCK + threadIdx.x;   // f32x4 index
  if (i >= N4) return;
  f32x4 v = ((const f32x4*)spec)[i];
  unsigned p0 = (unsigned)(2 * i);                 // pair idx of (v.x,v.y)
  unsigned f0 = p0 / 161u;                         // frame (magic mul)
  unsigned r  = p0 - f0 * 161u;
  unsigned f1 = f0 + (r == 160u);                  // frame of second pair
  float i0 = inv_g[f0];
  float i1 = inv_g[f1];
  f32x4 rr;
  rr.x = v.x * i0; rr.y = v.y * i0;
  rr.z = v.z * i1; rr.w = v.w * i1;
  // nt store: don't evict spec from caches with the write stream
  __builtin_nontemporal_store(rr, (f32x4*)out + i);
}

extern "C" void kernel_launch(void* const* d_in, const int* in_sizes, int n_in,
                              void* d_out, int out_size, void* d_ws, size_t ws_size,
                              hipStream_t stream) {
  const float* spec = (const float*)d_in[0];
  float* out   = (float*)d_out;
  float* gain  = out + N_SPEC;       // gain output lives in the d_out tail
  float* g0    = (float*)d_ws;       // 128000 f32
  float* inv_g = g0 + FRAMES;        // 128000 f32

  // K1: 32 groups (64 frames) per block -> 2000 blocks
  k_frame_gain<<<NGROUPS * 8 / BLOCK, BLOCK, 0, stream>>>(spec, g0);

  // K2: (16, 32) grid
  dim3 g2((T_SZ + 255) / 256, B_SZ);
  k_ema<<<g2, BLOCK, 0, stream>>>(g0, gain, inv_g);

  // K3: flat one-shot, 40250 blocks
  k_apply<<<(int)((N4 + BLOCK - 1) / BLOCK), BLOCK, 0, stream>>>(spec, inv_g, out);
}